// Round 4
// baseline (468.448 us; speedup 1.0000x reference)
//
#include <hip/hip_runtime.h>
#include <hip/hip_bf16.h>
#include <math.h>

typedef __bf16 bf16_t;
typedef bf16_t bf16x8 __attribute__((ext_vector_type(8)));
typedef float f32x4 __attribute__((ext_vector_type(4)));

#define WAYS 5
#define SHOTS 5
#define F_DIM 1024
#define HID 512
#define BATCH 2048
#define NN 26
#define NC 6
#define MROWS (BATCH * NC)   // 12288

#define S1 (HID * F_DIM)     // w1: 524288
#define S2 (HID * HID)       // w2: 262144
#define S3 (F_DIM * HID)     // w3: 524288

#define TM 48                // fused kernel rows/block -> 256 blocks = 1/CU
#define PADX 520             // LDS row stride (bf16): 1040 B, 16B-aligned, +4-bank/row swizzle

// ---------------- one-shot f32 -> bf16 convert of all three weights ----------------
__global__ __launch_bounds__(256)
void cvt_all_kernel(const float* __restrict__ w1, const float* __restrict__ w2,
                    const float* __restrict__ w3, bf16_t* __restrict__ out) {
    int i = (blockIdx.x * 256 + threadIdx.x) * 4;
    if (i >= S1 + S2 + S3) return;
    const float* src;
    int j = i;
    if (i < S1)            { src = w1; }
    else if (i < S1 + S2)  { src = w2; j = i - S1; }
    else                   { src = w3; j = i - S1 - S2; }
    float4 v = *(const float4*)(src + j);
    out[i + 0] = (bf16_t)v.x;
    out[i + 1] = (bf16_t)v.y;
    out[i + 2] = (bf16_t)v.z;
    out[i + 3] = (bf16_t)v.w;
}

// ------- Kernel 1: compact nf (5 way-means + query row) -> bf16 [12288,1024] -------
__global__ __launch_bounds__(128)
void nfc_kernel(const float* __restrict__ node, bf16_t* __restrict__ nfc_b) {
    int row = blockIdx.x;          // b*6 + w
    int b = row / NC;
    int w = row - b * NC;
    int f = threadIdx.x * 8;
    const float* src = node + (size_t)b * NN * F_DIM;
    float acc[8];
    if (w < WAYS) {
        #pragma unroll
        for (int e = 0; e < 8; ++e) acc[e] = 0.f;
        #pragma unroll
        for (int s = 0; s < SHOTS; ++s) {
            const float* r = src + (size_t)(w * SHOTS + s) * F_DIM + f;
            float4 v0 = *(const float4*)r;
            float4 v1 = *(const float4*)(r + 4);
            acc[0] += v0.x; acc[1] += v0.y; acc[2] += v0.z; acc[3] += v0.w;
            acc[4] += v1.x; acc[5] += v1.y; acc[6] += v1.z; acc[7] += v1.w;
        }
        #pragma unroll
        for (int e = 0; e < 8; ++e) acc[e] *= 0.2f;
    } else {
        const float* r = src + (size_t)25 * F_DIM + f;
        float4 v0 = *(const float4*)r;
        float4 v1 = *(const float4*)(r + 4);
        acc[0] = v0.x; acc[1] = v0.y; acc[2] = v0.z; acc[3] = v0.w;
        acc[4] = v1.x; acc[5] = v1.y; acc[6] = v1.z; acc[7] = v1.w;
    }
    bf16x8 ob;
    #pragma unroll
    for (int e = 0; e < 8; ++e) ob[e] = (bf16_t)acc[e];
    *(bf16x8*)(nfc_b + (size_t)row * F_DIM + f) = ob;
}

// -------- Fused MLP: nfc[48,1024] -> x1[48,512] -> x2[48,512] -> att[48,1024] --------
// Per block: 48 rows, full N. Waves partition N into 4 x 128. Weights register-direct
// from L2 (no LDS staging, no per-iter barriers). x1/x2 in LDS. 2 barriers total.
__global__ __launch_bounds__(256)
void fused_mlp(const bf16_t* __restrict__ nfc, const bf16_t* __restrict__ w1b,
               const bf16_t* __restrict__ w2b, const bf16_t* __restrict__ w3b,
               bf16_t* __restrict__ att,
               const float* __restrict__ b1, const float* __restrict__ g1,
               const float* __restrict__ be1, const float* __restrict__ m1,
               const float* __restrict__ v1,
               const float* __restrict__ b2, const float* __restrict__ g2,
               const float* __restrict__ be2, const float* __restrict__ m2,
               const float* __restrict__ v2,
               const float* __restrict__ b3) {
    __shared__ bf16_t X1[TM * PADX];
    __shared__ bf16_t X2[TM * PADX];
    const int tid = threadIdx.x;
    const int lane = tid & 63;
    const int wv = tid >> 6;
    const int l15 = lane & 15, quad = lane >> 4;
    const int bm = blockIdx.x * TM;
    const int nb = wv * 128;          // wave's n-base within a 512 stripe

    f32x4 acc[3][8];

    // MFMA step over one 64-wide K chunk: 48 MFMAs, acc dep distance 24
    auto mmac = [&](bf16x8 (&af)[6], bf16x8 (&bf)[16]) {
        #pragma unroll
        for (int kk = 0; kk < 2; ++kk)
            #pragma unroll
            for (int mt = 0; mt < 3; ++mt)
                #pragma unroll
                for (int nt = 0; nt < 8; ++nt)
                    acc[mt][nt] = __builtin_amdgcn_mfma_f32_16x16x32_bf16(
                        af[mt * 2 + kk], bf[nt * 2 + kk], acc[mt][nt], 0, 0, 0);
    };
    // B-frags (weights) register-direct: rows = out-channels, 16 B per lane
    auto ldB = [&](bf16x8 (&bf)[16], const bf16_t* W, int K, int c) {
        #pragma unroll
        for (int nt = 0; nt < 8; ++nt)
            #pragma unroll
            for (int kk = 0; kk < 2; ++kk)
                bf[nt * 2 + kk] = *(const bf16x8*)(W + (size_t)(nb + nt * 16 + l15) * K
                                                   + c * 64 + kk * 32 + quad * 8);
    };
    // A-frags from global nfc (stage 1; identical addrs across waves -> L1 dedupe)
    auto ldA1 = [&](bf16x8 (&af)[6], int c) {
        #pragma unroll
        for (int mt = 0; mt < 3; ++mt)
            #pragma unroll
            for (int kk = 0; kk < 2; ++kk)
                af[mt * 2 + kk] = *(const bf16x8*)(nfc + (size_t)(bm + mt * 16 + l15) * F_DIM
                                                    + c * 64 + kk * 32 + quad * 8);
    };
    // A-frags from LDS (stages 2/3); `which` is constant at every call site
    auto ldAx = [&](bf16x8 (&af)[6], int which, int c) {
        #pragma unroll
        for (int mt = 0; mt < 3; ++mt)
            #pragma unroll
            for (int kk = 0; kk < 2; ++kk) {
                int idx = (mt * 16 + l15) * PADX + c * 64 + kk * 32 + quad * 8;
                af[mt * 2 + kk] = which ? *(const bf16x8*)&X2[idx] : *(const bf16x8*)&X1[idx];
            }
    };

    bf16x8 aF0[6], aF1[6], bF0[16], bF1[16];

    // ================= Stage 1: x1 = lrelu(bn1(nfc @ w1^T)) =================
    #pragma unroll
    for (int mt = 0; mt < 3; ++mt)
        #pragma unroll
        for (int nt = 0; nt < 8; ++nt)
            acc[mt][nt] = (f32x4){0.f, 0.f, 0.f, 0.f};
    ldA1(aF0, 0); ldB(bF0, w1b, F_DIM, 0);
    for (int c = 0; c < 16; c += 2) {
        ldA1(aF1, c + 1); ldB(bF1, w1b, F_DIM, c + 1);
        mmac(aF0, bF0);
        if (c + 2 < 16) { ldA1(aF0, c + 2); ldB(bF0, w1b, F_DIM, c + 2); }
        mmac(aF1, bF1);
    }
    #pragma unroll
    for (int nt = 0; nt < 8; ++nt) {
        const int n = nb + nt * 16 + l15;
        const float sg = g1[n] * rsqrtf(v1[n] + 1e-5f);
        const float tt = (b1[n] - m1[n]) * sg + be1[n];
        #pragma unroll
        for (int mt = 0; mt < 3; ++mt) {
            const int row = mt * 16 + quad * 4;
            #pragma unroll
            for (int r = 0; r < 4; ++r) {
                float y = acc[mt][nt][r] * sg + tt;
                y = y > 0.f ? y : 0.01f * y;
                X1[(row + r) * PADX + n] = (bf16_t)y;
            }
        }
    }
    __syncthreads();

    // ================= Stage 2: x2 = lrelu(bn2(x1 @ w2^T)) =================
    #pragma unroll
    for (int mt = 0; mt < 3; ++mt)
        #pragma unroll
        for (int nt = 0; nt < 8; ++nt)
            acc[mt][nt] = (f32x4){0.f, 0.f, 0.f, 0.f};
    ldB(bF0, w2b, HID, 0);
    for (int c = 0; c < 8; c += 2) {
        ldB(bF1, w2b, HID, c + 1);
        ldAx(aF0, 0, c);
        mmac(aF0, bF0);
        if (c + 2 < 8) ldB(bF0, w2b, HID, c + 2);
        ldAx(aF1, 0, c + 1);
        mmac(aF1, bF1);
    }
    #pragma unroll
    for (int nt = 0; nt < 8; ++nt) {
        const int n = nb + nt * 16 + l15;
        const float sg = g2[n] * rsqrtf(v2[n] + 1e-5f);
        const float tt = (b2[n] - m2[n]) * sg + be2[n];
        #pragma unroll
        for (int mt = 0; mt < 3; ++mt) {
            const int row = mt * 16 + quad * 4;
            #pragma unroll
            for (int r = 0; r < 4; ++r) {
                float y = acc[mt][nt][r] * sg + tt;
                y = y > 0.f ? y : 0.01f * y;
                X2[(row + r) * PADX + n] = (bf16_t)y;
            }
        }
    }
    __syncthreads();

    // ============ Stage 3: att = sigmoid(x2 @ w3^T + b3), two N-halves ============
    #pragma unroll
    for (int h = 0; h < 2; ++h) {
        const bf16_t* w3h = w3b + (size_t)(h * 512) * HID;
        #pragma unroll
        for (int mt = 0; mt < 3; ++mt)
            #pragma unroll
            for (int nt = 0; nt < 8; ++nt)
                acc[mt][nt] = (f32x4){0.f, 0.f, 0.f, 0.f};
        ldB(bF0, w3h, HID, 0);
        for (int c = 0; c < 8; c += 2) {
            ldB(bF1, w3h, HID, c + 1);
            ldAx(aF0, 1, c);
            mmac(aF0, bF0);
            if (c + 2 < 8) ldB(bF0, w3h, HID, c + 2);
            ldAx(aF1, 1, c + 1);
            mmac(aF1, bF1);
        }
        #pragma unroll
        for (int nt = 0; nt < 8; ++nt) {
            const int n = h * 512 + nb + nt * 16 + l15;
            const float tt = b3[n];
            #pragma unroll
            for (int mt = 0; mt < 3; ++mt) {
                const int m = bm + mt * 16 + quad * 4;
                #pragma unroll
                for (int r = 0; r < 4; ++r) {
                    float y = acc[mt][nt][r] + tt;
                    y = 1.0f / (1.0f + __expf(-y));
                    att[(size_t)(m + r) * F_DIM + n] = (bf16_t)y;
                }
            }
        }
    }
}

// ------- Kernel 5: per-episode 6x6 sims (bf16 inputs), expand to [2,26,26] f32 -------
__global__ __launch_bounds__(256)
void sim_kernel(const bf16_t* __restrict__ nfc, const bf16_t* __restrict__ att,
                float* __restrict__ out) {
    __shared__ float sx[NC * F_DIM];
    __shared__ float sa[NC * F_DIM];
    __shared__ float dmat[NC * NC], n2mat[NC * NC], simc[NC * NC];
    const int b = blockIdx.x, tid = threadIdx.x;
    const bf16_t* xs = nfc + (size_t)b * NC * F_DIM;
    const bf16_t* as = att + (size_t)b * NC * F_DIM;
    for (int i = tid * 8; i < NC * F_DIM; i += 256 * 8) {
        bf16x8 vx = *(const bf16x8*)&xs[i];
        bf16x8 va = *(const bf16x8*)&as[i];
        #pragma unroll
        for (int e = 0; e < 8; ++e) { sx[i + e] = (float)vx[e]; sa[i + e] = (float)va[e]; }
    }
    __syncthreads();
    const int lane = tid & 63, wid = tid >> 6;
    const int ti[21] = {0,0,0,0,0,0,1,1,1,1,1,2,2,2,2,3,3,3,4,4,5};
    const int tj[21] = {0,1,2,3,4,5,1,2,3,4,5,2,3,4,5,3,4,5,4,5,5};
    for (int t = wid; t < 21; t += 4) {
        const int i = ti[t], j = tj[t];
        float d = 0.f, qij = 0.f, qji = 0.f;
        for (int f = lane; f < F_DIM; f += 64) {
            float ai = sa[i * F_DIM + f], aj = sa[j * F_DIM + f];
            float xi = sx[i * F_DIM + f], xj = sx[j * F_DIM + f];
            float a2i = ai * ai, a2j = aj * aj;
            float pi = a2i * xi, pj = a2j * xj;
            d   += pi * pj;
            qij += pi * xi * a2j;
            qji += pj * xj * a2i;
        }
        #pragma unroll
        for (int off = 32; off > 0; off >>= 1) {
            d   += __shfl_xor(d, off);
            qij += __shfl_xor(qij, off);
            qji += __shfl_xor(qji, off);
        }
        if (lane == 0) {
            dmat[i * NC + j] = d; dmat[j * NC + i] = d;
            n2mat[i * NC + j] = qij; n2mat[j * NC + i] = qji;
        }
    }
    __syncthreads();
    if (tid < NC * NC) {
        int i = tid / NC, j = tid - (tid / NC) * NC;
        simc[tid] = dmat[tid] / sqrtf(n2mat[i * NC + j] * n2mat[j * NC + i]);
    }
    __syncthreads();
    float* o = out + (size_t)b * (2 * NN * NN);
    for (int e = tid; e < 2 * NN * NN; e += 256) {
        int ch = e / (NN * NN);
        int rem = e - ch * (NN * NN);
        int i = rem / NN, j = rem - (rem / NN) * NN;
        float s = simc[(i / 5) * NC + (j / 5)];
        float v = ch ? 1.0f - s : s;
        v = fminf(fmaxf(v, 0.0f), 1.0f);
        o[e] = v;
    }
}

extern "C" void kernel_launch(void* const* d_in, const int* in_sizes, int n_in,
                              void* d_out, int out_size, void* d_ws, size_t ws_size,
                              hipStream_t stream) {
    const float* node = (const float*)d_in[0];
    const float* w1  = (const float*)d_in[1];
    const float* b1  = (const float*)d_in[2];
    const float* g1  = (const float*)d_in[3];
    const float* be1 = (const float*)d_in[4];
    const float* m1  = (const float*)d_in[5];
    const float* v1  = (const float*)d_in[6];
    const float* w2  = (const float*)d_in[7];
    const float* b2  = (const float*)d_in[8];
    const float* g2  = (const float*)d_in[9];
    const float* be2 = (const float*)d_in[10];
    const float* m2  = (const float*)d_in[11];
    const float* v2  = (const float*)d_in[12];
    const float* w3  = (const float*)d_in[13];
    const float* b3  = (const float*)d_in[14];
    float* out = (float*)d_out;

    char* ws = (char*)d_ws;
    size_t off = 0;
    bf16_t* wall  = (bf16_t*)(ws + off); off += (size_t)(S1 + S2 + S3) * 2;   // 2.62 MB
    bf16_t* w1b = wall, *w2b = wall + S1, *w3b = wall + S1 + S2;
    bf16_t* nfc_b = (bf16_t*)(ws + off); off += (size_t)MROWS * F_DIM * 2;    // 25.2 MB
    bf16_t* attb  = (bf16_t*)(ws + off); off += (size_t)MROWS * F_DIM * 2;    // 25.2 MB

    cvt_all_kernel<<<((S1 + S2 + S3) / 4 + 255) / 256, 256, 0, stream>>>(w1, w2, w3, wall);
    nfc_kernel<<<MROWS, 128, 0, stream>>>(node, nfc_b);
    fused_mlp<<<MROWS / TM, 256, 0, stream>>>(nfc_b, w1b, w2b, w3b, attb,
                                              b1, g1, be1, m1, v1,
                                              b2, g2, be2, m2, v2, b3);
    sim_kernel<<<BATCH, 256, 0, stream>>>(nfc_b, attb, out);
}

// Round 5
// 465.847 us; speedup vs baseline: 1.0056x; 1.0056x over previous
//
#include <hip/hip_runtime.h>
#include <hip/hip_bf16.h>
#include <math.h>

typedef __bf16 bf16_t;
typedef bf16_t bf16x8 __attribute__((ext_vector_type(8)));
typedef float f32x4 __attribute__((ext_vector_type(4)));

#define WAYS 5
#define SHOTS 5
#define F_DIM 1024
#define HID 512
#define BATCH 2048
#define NN 26
#define NC 6
#define MROWS (BATCH * NC)   // 12288

#define S1 (HID * F_DIM)     // w1: 524288
#define S2 (HID * HID)       // w2: 262144
#define S3 (F_DIM * HID)     // w3: 524288

#define TM 48                // rows/block -> 256 blocks = 1/CU
#define PADX 520             // LDS row stride (bf16): +4-bank/row swizzle -> 2-way (free)

// ---------------- one-shot f32 -> bf16 convert of all three weights ----------------
__global__ __launch_bounds__(256)
void cvt_all_kernel(const float* __restrict__ w1, const float* __restrict__ w2,
                    const float* __restrict__ w3, bf16_t* __restrict__ out) {
    int i = (blockIdx.x * 256 + threadIdx.x) * 4;
    if (i >= S1 + S2 + S3) return;
    const float* src;
    int j = i;
    if (i < S1)            { src = w1; }
    else if (i < S1 + S2)  { src = w2; j = i - S1; }
    else                   { src = w3; j = i - S1 - S2; }
    float4 v = *(const float4*)(src + j);
    out[i + 0] = (bf16_t)v.x;
    out[i + 1] = (bf16_t)v.y;
    out[i + 2] = (bf16_t)v.z;
    out[i + 3] = (bf16_t)v.w;
}

// ------- Kernel 1: compact nf (5 way-means + query row) -> bf16 [12288,1024] -------
__global__ __launch_bounds__(128)
void nfc_kernel(const float* __restrict__ node, bf16_t* __restrict__ nfc_b) {
    int row = blockIdx.x;          // b*6 + w
    int b = row / NC;
    int w = row - b * NC;
    int f = threadIdx.x * 8;
    const float* src = node + (size_t)b * NN * F_DIM;
    float acc[8];
    if (w < WAYS) {
        #pragma unroll
        for (int e = 0; e < 8; ++e) acc[e] = 0.f;
        #pragma unroll
        for (int s = 0; s < SHOTS; ++s) {
            const float* r = src + (size_t)(w * SHOTS + s) * F_DIM + f;
            float4 v0 = *(const float4*)r;
            float4 v1 = *(const float4*)(r + 4);
            acc[0] += v0.x; acc[1] += v0.y; acc[2] += v0.z; acc[3] += v0.w;
            acc[4] += v1.x; acc[5] += v1.y; acc[6] += v1.z; acc[7] += v1.w;
        }
        #pragma unroll
        for (int e = 0; e < 8; ++e) acc[e] *= 0.2f;
    } else {
        const float* r = src + (size_t)25 * F_DIM + f;
        float4 v0 = *(const float4*)r;
        float4 v1 = *(const float4*)(r + 4);
        acc[0] = v0.x; acc[1] = v0.y; acc[2] = v0.z; acc[3] = v0.w;
        acc[4] = v1.x; acc[5] = v1.y; acc[6] = v1.z; acc[7] = v1.w;
    }
    bf16x8 ob;
    #pragma unroll
    for (int e = 0; e < 8; ++e) ob[e] = (bf16_t)acc[e];
    *(bf16x8*)(nfc_b + (size_t)row * F_DIM + f) = ob;
}

// -------- Fused MLP: nfc[48,1024] -> x1[48,512] -> x2[48,512] -> att[48,1024] --------
// 512 threads / 8 waves; wave w owns a 64-wide N stripe. Weights register-direct from
// L2 (no LDS staging, no per-iter barriers). x1/x2 in LDS. 2 barriers total.
// Regs: acc 48 + aF 2x24 + bF 2x32 ~ 160 + misc -> fits 256 (2 waves/SIMD).
__global__ __launch_bounds__(512, 2)
void fused_mlp(const bf16_t* __restrict__ nfc, const bf16_t* __restrict__ w1b,
               const bf16_t* __restrict__ w2b, const bf16_t* __restrict__ w3b,
               bf16_t* __restrict__ att,
               const float* __restrict__ b1, const float* __restrict__ g1,
               const float* __restrict__ be1, const float* __restrict__ m1,
               const float* __restrict__ v1,
               const float* __restrict__ b2, const float* __restrict__ g2,
               const float* __restrict__ be2, const float* __restrict__ m2,
               const float* __restrict__ v2,
               const float* __restrict__ b3) {
    __shared__ bf16_t X1[TM * PADX];
    __shared__ bf16_t X2[TM * PADX];
    const int tid = threadIdx.x;
    const int lane = tid & 63;
    const int wv = tid >> 6;              // 0..7
    const int l15 = lane & 15, quad = lane >> 4;
    const int bm = blockIdx.x * TM;
    const int nb = wv * 64;               // wave's n-base within a 512 stripe

    f32x4 acc[3][4];

    // one 64-wide K chunk: 24 MFMAs, same-acc dep distance 12
    auto mmac = [&](bf16x8 (&af)[6], bf16x8 (&bf)[8]) {
        #pragma unroll
        for (int kk = 0; kk < 2; ++kk)
            #pragma unroll
            for (int mt = 0; mt < 3; ++mt)
                #pragma unroll
                for (int nt = 0; nt < 4; ++nt)
                    acc[mt][nt] = __builtin_amdgcn_mfma_f32_16x16x32_bf16(
                        af[mt * 2 + kk], bf[nt * 2 + kk], acc[mt][nt], 0, 0, 0);
    };
    auto zacc = [&]() {
        #pragma unroll
        for (int mt = 0; mt < 3; ++mt)
            #pragma unroll
            for (int nt = 0; nt < 4; ++nt)
                acc[mt][nt] = (f32x4){0.f, 0.f, 0.f, 0.f};
    };
    // B-frags (weights) register-direct: rows = out-channels
    auto ldB = [&](bf16x8 (&bf)[8], const bf16_t* W, int K, int c) {
        #pragma unroll
        for (int nt = 0; nt < 4; ++nt)
            #pragma unroll
            for (int kk = 0; kk < 2; ++kk)
                bf[nt * 2 + kk] = *(const bf16x8*)(W + (size_t)(nb + nt * 16 + l15) * K
                                                   + c * 64 + kk * 32 + quad * 8);
    };
    // A-frags from global nfc (stage 1; identical addrs across waves -> L1 hits)
    auto ldA1 = [&](bf16x8 (&af)[6], int c) {
        #pragma unroll
        for (int mt = 0; mt < 3; ++mt)
            #pragma unroll
            for (int kk = 0; kk < 2; ++kk)
                af[mt * 2 + kk] = *(const bf16x8*)(nfc + (size_t)(bm + mt * 16 + l15) * F_DIM
                                                    + c * 64 + kk * 32 + quad * 8);
    };
    // A-frags from LDS (stages 2/3); `which` constant at each call site
    auto ldAx = [&](bf16x8 (&af)[6], int which, int c) {
        #pragma unroll
        for (int mt = 0; mt < 3; ++mt)
            #pragma unroll
            for (int kk = 0; kk < 2; ++kk) {
                int idx = (mt * 16 + l15) * PADX + c * 64 + kk * 32 + quad * 8;
                af[mt * 2 + kk] = which ? *(const bf16x8*)&X2[idx] : *(const bf16x8*)&X1[idx];
            }
    };

    bf16x8 aF0[6], aF1[6], bF0[8], bF1[8];

    // ================= Stage 1: x1 = lrelu(bn1(nfc @ w1^T)) =================
    zacc();
    ldA1(aF0, 0); ldB(bF0, w1b, F_DIM, 0);
    for (int c = 0; c < 16; c += 2) {
        ldA1(aF1, c + 1); ldB(bF1, w1b, F_DIM, c + 1);
        mmac(aF0, bF0);
        if (c + 2 < 16) { ldA1(aF0, c + 2); ldB(bF0, w1b, F_DIM, c + 2); }
        mmac(aF1, bF1);
    }
    #pragma unroll
    for (int nt = 0; nt < 4; ++nt) {
        const int n = nb + nt * 16 + l15;
        const float sg = g1[n] * rsqrtf(v1[n] + 1e-5f);
        const float tt = (b1[n] - m1[n]) * sg + be1[n];
        #pragma unroll
        for (int mt = 0; mt < 3; ++mt) {
            const int row = mt * 16 + quad * 4;
            #pragma unroll
            for (int r = 0; r < 4; ++r) {
                float y = acc[mt][nt][r] * sg + tt;
                y = y > 0.f ? y : 0.01f * y;
                X1[(row + r) * PADX + n] = (bf16_t)y;
            }
        }
    }
    __syncthreads();

    // ================= Stage 2: x2 = lrelu(bn2(x1 @ w2^T)) =================
    zacc();
    ldAx(aF0, 0, 0); ldB(bF0, w2b, HID, 0);
    for (int c = 0; c < 8; c += 2) {
        ldAx(aF1, 0, c + 1); ldB(bF1, w2b, HID, c + 1);
        mmac(aF0, bF0);
        if (c + 2 < 8) { ldAx(aF0, 0, c + 2); ldB(bF0, w2b, HID, c + 2); }
        mmac(aF1, bF1);
    }
    #pragma unroll
    for (int nt = 0; nt < 4; ++nt) {
        const int n = nb + nt * 16 + l15;
        const float sg = g2[n] * rsqrtf(v2[n] + 1e-5f);
        const float tt = (b2[n] - m2[n]) * sg + be2[n];
        #pragma unroll
        for (int mt = 0; mt < 3; ++mt) {
            const int row = mt * 16 + quad * 4;
            #pragma unroll
            for (int r = 0; r < 4; ++r) {
                float y = acc[mt][nt][r] * sg + tt;
                y = y > 0.f ? y : 0.01f * y;
                X2[(row + r) * PADX + n] = (bf16_t)y;
            }
        }
    }
    __syncthreads();

    // ============ Stage 3: att = sigmoid(x2 @ w3^T + b3), two N-halves ============
    #pragma unroll
    for (int h = 0; h < 2; ++h) {
        const bf16_t* w3h = w3b + (size_t)(h * 512) * HID;
        zacc();
        ldAx(aF0, 1, 0); ldB(bF0, w3h, HID, 0);
        for (int c = 0; c < 8; c += 2) {
            ldAx(aF1, 1, c + 1); ldB(bF1, w3h, HID, c + 1);
            mmac(aF0, bF0);
            if (c + 2 < 8) { ldAx(aF0, 1, c + 2); ldB(bF0, w3h, HID, c + 2); }
            mmac(aF1, bF1);
        }
        #pragma unroll
        for (int nt = 0; nt < 4; ++nt) {
            const int n = h * 512 + nb + nt * 16 + l15;
            const float tt = b3[n];
            #pragma unroll
            for (int mt = 0; mt < 3; ++mt) {
                const int m = bm + mt * 16 + quad * 4;
                #pragma unroll
                for (int r = 0; r < 4; ++r) {
                    float y = acc[mt][nt][r] + tt;
                    y = 1.0f / (1.0f + __expf(-y));
                    att[(size_t)(m + r) * F_DIM + n] = (bf16_t)y;
                }
            }
        }
    }
}

// ------- Kernel 5: per-episode 6x6 sims (bf16 inputs), expand to [2,26,26] f32 -------
__global__ __launch_bounds__(256)
void sim_kernel(const bf16_t* __restrict__ nfc, const bf16_t* __restrict__ att,
                float* __restrict__ out) {
    __shared__ float sx[NC * F_DIM];
    __shared__ float sa[NC * F_DIM];
    __shared__ float dmat[NC * NC], n2mat[NC * NC], simc[NC * NC];
    const int b = blockIdx.x, tid = threadIdx.x;
    const bf16_t* xs = nfc + (size_t)b * NC * F_DIM;
    const bf16_t* as = att + (size_t)b * NC * F_DIM;
    for (int i = tid * 8; i < NC * F_DIM; i += 256 * 8) {
        bf16x8 vx = *(const bf16x8*)&xs[i];
        bf16x8 va = *(const bf16x8*)&as[i];
        #pragma unroll
        for (int e = 0; e < 8; ++e) { sx[i + e] = (float)vx[e]; sa[i + e] = (float)va[e]; }
    }
    __syncthreads();
    const int lane = tid & 63, wid = tid >> 6;
    const int ti[21] = {0,0,0,0,0,0,1,1,1,1,1,2,2,2,2,3,3,3,4,4,5};
    const int tj[21] = {0,1,2,3,4,5,1,2,3,4,5,2,3,4,5,3,4,5,4,5,5};
    for (int t = wid; t < 21; t += 4) {
        const int i = ti[t], j = tj[t];
        float d = 0.f, qij = 0.f, qji = 0.f;
        for (int f = lane; f < F_DIM; f += 64) {
            float ai = sa[i * F_DIM + f], aj = sa[j * F_DIM + f];
            float xi = sx[i * F_DIM + f], xj = sx[j * F_DIM + f];
            float a2i = ai * ai, a2j = aj * aj;
            float pi = a2i * xi, pj = a2j * xj;
            d   += pi * pj;
            qij += pi * xi * a2j;
            qji += pj * xj * a2i;
        }
        #pragma unroll
        for (int off = 32; off > 0; off >>= 1) {
            d   += __shfl_xor(d, off);
            qij += __shfl_xor(qij, off);
            qji += __shfl_xor(qji, off);
        }
        if (lane == 0) {
            dmat[i * NC + j] = d; dmat[j * NC + i] = d;
            n2mat[i * NC + j] = qij; n2mat[j * NC + i] = qji;
        }
    }
    __syncthreads();
    if (tid < NC * NC) {
        int i = tid / NC, j = tid - (tid / NC) * NC;
        simc[tid] = dmat[tid] / sqrtf(n2mat[i * NC + j] * n2mat[j * NC + i]);
    }
    __syncthreads();
    float* o = out + (size_t)b * (2 * NN * NN);
    for (int e = tid; e < 2 * NN * NN; e += 256) {
        int ch = e / (NN * NN);
        int rem = e - ch * (NN * NN);
        int i = rem / NN, j = rem - (rem / NN) * NN;
        float s = simc[(i / 5) * NC + (j / 5)];
        float v = ch ? 1.0f - s : s;
        v = fminf(fmaxf(v, 0.0f), 1.0f);
        o[e] = v;
    }
}

extern "C" void kernel_launch(void* const* d_in, const int* in_sizes, int n_in,
                              void* d_out, int out_size, void* d_ws, size_t ws_size,
                              hipStream_t stream) {
    const float* node = (const float*)d_in[0];
    const float* w1  = (const float*)d_in[1];
    const float* b1  = (const float*)d_in[2];
    const float* g1  = (const float*)d_in[3];
    const float* be1 = (const float*)d_in[4];
    const float* m1  = (const float*)d_in[5];
    const float* v1  = (const float*)d_in[6];
    const float* w2  = (const float*)d_in[7];
    const float* b2  = (const float*)d_in[8];
    const float* g2  = (const float*)d_in[9];
    const float* be2 = (const float*)d_in[10];
    const float* m2  = (const float*)d_in[11];
    const float* v2  = (const float*)d_in[12];
    const float* w3  = (const float*)d_in[13];
    const float* b3  = (const float*)d_in[14];
    float* out = (float*)d_out;

    char* ws = (char*)d_ws;
    size_t off = 0;
    bf16_t* wall  = (bf16_t*)(ws + off); off += (size_t)(S1 + S2 + S3) * 2;   // 2.62 MB
    bf16_t* w1b = wall, *w2b = wall + S1, *w3b = wall + S1 + S2;
    bf16_t* nfc_b = (bf16_t*)(ws + off); off += (size_t)MROWS * F_DIM * 2;    // 25.2 MB
    bf16_t* attb  = (bf16_t*)(ws + off); off += (size_t)MROWS * F_DIM * 2;    // 25.2 MB

    cvt_all_kernel<<<((S1 + S2 + S3) / 4 + 255) / 256, 256, 0, stream>>>(w1, w2, w3, wall);
    nfc_kernel<<<MROWS, 128, 0, stream>>>(node, nfc_b);
    fused_mlp<<<MROWS / TM, 512, 0, stream>>>(nfc_b, w1b, w2b, w3b, attb,
                                              b1, g1, be1, m1, v1,
                                              b2, g2, be2, m2, v2, b3);
    sim_kernel<<<BATCH, 256, 0, stream>>>(nfc_b, attb, out);
}